// Round 2
// baseline (551.860 us; speedup 1.0000x reference)
//
#include <hip/hip_runtime.h>
#include <hip/hip_bf16.h>

typedef __bf16 bf16;
typedef __bf16 bf16x4 __attribute__((ext_vector_type(4)));
typedef __bf16 bf16x8 __attribute__((ext_vector_type(8)));
typedef float f32x4 __attribute__((ext_vector_type(4)));

// problem sizes
#define NN 8192
#define DIN 128
#define DTH 256
#define DH 64

// workspace layout (bytes) -- ws is >= 1 GiB (harness poisons 1 GiB)
#define OFF_BN   0                               // 256 f32 bn sums (1 KB)
#define OFF_PACC 1024                            // 2 (js) * 8192*64 f32
#define OFF_PDEN (OFF_PACC + 2*8192*64*4)        // 2 (js) * 8192 f32
#define OFF_HX   (OFF_PDEN + 2*8192*4)           // 8192*256 bf16 Hx
#define OFF_X2T  (OFF_HX + 8192*256*2)           // 64*8192 bf16 X2 transposed
#define OFF_AM   (OFF_X2T + 64*8192*2)           // 8192*256 u32 adjacency bitmask
#define ZERO_BYTES 1024                          // only bn sums need zeroing

#define E_CONST 2.71828182845904523f

// ---------------------------------------------------------------------------
// Pack adjacency to bits: Am[i][w] bit b = (A[i][w*32+b] > 0).
// Pure streaming kernel: 256 MB read at HBM BW, 8 MB written.
__global__ __launch_bounds__(256) void k_pack(const float* __restrict__ A,
                                              unsigned* __restrict__ Am)
{
    int row = blockIdx.x, t = threadIdx.x;
    const float* p = A + (size_t)row * NN + t * 32;
    unsigned m = 0;
#pragma unroll
    for (int u = 0; u < 8; ++u) {
        f32x4 v = *(const f32x4*)(p + u * 4);
        m |= (v[0] > 0.f ? 1u : 0u) << (u * 4 + 0);
        m |= (v[1] > 0.f ? 1u : 0u) << (u * 4 + 1);
        m |= (v[2] > 0.f ? 1u : 0u) << (u * 4 + 2);
        m |= (v[3] > 0.f ? 1u : 0u) << (u * 4 + 3);
    }
    Am[(size_t)row * 256 + t] = m;
}

// ---------------------------------------------------------------------------
// BN statistics: per-feature sum and sum-of-squares via per-block partials.
__global__ __launch_bounds__(256) void k_bn_stats(const float* __restrict__ H,
                                                  float* __restrict__ bns) {
    __shared__ float s1[256], s2[256];
    int t = threadIdx.x;
    int f = t & 127, rh = t >> 7;
    int r0 = blockIdx.x * 32 + rh * 16;
    float a = 0.f, b = 0.f;
#pragma unroll
    for (int rr = 0; rr < 16; ++rr) {
        float x = H[(size_t)(r0 + rr) * DIN + f];
        a += x; b += x * x;
    }
    s1[t] = a; s2[t] = b;
    __syncthreads();
    if (t < 128) {
        atomicAdd(&bns[f], s1[t] + s1[t + 128]);
        atomicAdd(&bns[128 + f], s2[t] + s2[t + 128]);
    }
}

// ---------------------------------------------------------------------------
// BN apply + projections: Hx = Hn@Wt+bt (bf16), out1 = leaky(Hn@W1+b1) (fp32,
// written directly to left half of output), X2T[c][row] = Hn@W2+b2 (bf16).
__global__ __launch_bounds__(256) void k_project(
    const float* __restrict__ H, const float* __restrict__ bns,
    const float* __restrict__ gamma, const float* __restrict__ beta,
    const float* __restrict__ Wt, const float* __restrict__ bt,
    const float* __restrict__ W1, const float* __restrict__ b1,
    const float* __restrict__ W2, const float* __restrict__ b2,
    bf16* __restrict__ Hx, bf16* __restrict__ X2T, float* __restrict__ out)
{
    __shared__ float Hn[16 * 128];
    int t = threadIdx.x;
    int r0 = blockIdx.x * 16;
    {   // BN apply: each thread owns feature f = t&127, rows t>>7 + 2p
        int f = t & 127;
        float mean = bns[f] * (1.f / 8192.f);
        float var  = bns[128 + f] * (1.f / 8192.f) - mean * mean;
        float sc = rsqrtf(var + 1e-5f) * gamma[f];
        float sh = beta[f];
        int rb = t >> 7;
#pragma unroll
        for (int p = 0; p < 8; ++p) {
            int row = rb + p * 2;
            float x = H[(size_t)(r0 + row) * DIN + f];
            Hn[row * 128 + f] = (x - mean) * sc + sh;
        }
    }
    __syncthreads();
    {   // Hx = Hn @ Wt + bt : thread -> 4 rows x 4 cols
        int c0 = t & 63, rg = t >> 6;
        float acc[4][4];
#pragma unroll
        for (int i = 0; i < 4; ++i)
#pragma unroll
            for (int j = 0; j < 4; ++j) acc[i][j] = 0.f;
        for (int k = 0; k < 128; ++k) {
            float h[4];
#pragma unroll
            for (int rr = 0; rr < 4; ++rr) h[rr] = Hn[(rg * 4 + rr) * 128 + k];
#pragma unroll
            for (int cc = 0; cc < 4; ++cc) {
                float wv = Wt[k * DTH + c0 + 64 * cc];
#pragma unroll
                for (int rr = 0; rr < 4; ++rr) acc[rr][cc] += h[rr] * wv;
            }
        }
#pragma unroll
        for (int rr = 0; rr < 4; ++rr) {
            int row = r0 + rg * 4 + rr;
#pragma unroll
            for (int cc = 0; cc < 4; ++cc) {
                int c = c0 + 64 * cc;
                Hx[(size_t)row * DTH + c] = (bf16)(acc[rr][cc] + bt[c]);
            }
        }
    }
    {   // out1 (fp32 exact) and X2T (bf16)
        int c = t & 63, rg = t >> 6;
        float a1[4] = {0,0,0,0}, a2[4] = {0,0,0,0};
        for (int k = 0; k < 128; ++k) {
            float w1 = W1[k * DH + c], w2 = W2[k * DH + c];
#pragma unroll
            for (int rr = 0; rr < 4; ++rr) {
                float h = Hn[(rg * 4 + rr) * 128 + k];
                a1[rr] += h * w1; a2[rr] += h * w2;
            }
        }
#pragma unroll
        for (int rr = 0; rr < 4; ++rr) {
            int row = r0 + rg * 4 + rr;
            float v1 = a1[rr] + b1[c];
            out[(size_t)row * 128 + c] = v1 > 0.f ? v1 : 0.01f * v1;
            X2T[(size_t)c * NN + row] = (bf16)(a2[rr] + b2[c]);
        }
    }
}

// ---------------------------------------------------------------------------
// Fused v3: S^T = Hx_j @ Hx_i^T via mfma(A=Hx_j, B=Hx_i) so each lane holds
// P^T[j=4q+r][i=li] -- exactly the B-fragment positions for PV mfma.
//  - gate->PV is register-only (no P LDS round-trip, no mid-chunk barrier)
//  - PV pairs two 64-j chunks (K=32): even chunk stores pe, odd chunk fires
//    8 mfma with A = X2T fragments loaded direct from global (L2-resident)
//  - adjacency from 8 MB bitmask (1 u32/lane/chunk, prefetched 2 chunks)
//  - hxj double-buffered (2x32KB, XOR-swizzled), 1 barrier per chunk
//  - per-wave PV partials reduced via LDS at the end; js-split partial
//    buffers instead of atomics
__global__ __launch_bounds__(256, 2) void k_fused(
    const unsigned* __restrict__ Am, const bf16* __restrict__ Hx,
    const bf16* __restrict__ X2T, float* __restrict__ pacc,
    float* __restrict__ pden)
{
    __shared__ __align__(16) bf16 hxj[2][64 * 256];

    int t = threadIdx.x;
    int w = t >> 6, l = t & 63;
    int q = l >> 4, li = l & 15;
    int ib = blockIdx.x >> 1, js = blockIdx.x & 1;
    int i0 = ib * 32;
    int jb = js * 4096;

    // B-fragments of Hx_i (held in regs; col=li, k=q*8+e per k-slice)
    bf16x8 afragB[2][8];
#pragma unroll
    for (int n = 0; n < 2; ++n)
#pragma unroll
        for (int ks = 0; ks < 8; ++ks)
            afragB[n][ks] = *(const bf16x8*)&Hx[(size_t)(i0 + n * 16 + li) * DTH + ks * 32 + q * 8];

    // staging geometry: thread covers rows (t>>5)+8p, 16B chunk t&31
    int srow = t >> 5, sseg = t & 31;
    const bf16* hsrc = Hx + (size_t)(jb + srow) * DTH + sseg * 8;
    int sdst = (sseg ^ srow) * 8;          // phys 16B chunk = log ^ (row&7)

    // mask word pointers (per n-tile row), word index = jb/32 + w/2 + ch*2
    const unsigned* amr0 = Am + (size_t)(i0 + li) * 256 + (jb >> 5) + (w >> 1);
    const unsigned* amr1 = amr0 + (size_t)16 * 256;

    bf16x8 R[8];
    unsigned mwA[2], mwB[2];
    uint2 xe[4], xo[4];
    bf16x4 pe0, pe1;
    f32x4 acc[4][2] = {{{0,0,0,0},{0,0,0,0}},{{0,0,0,0},{0,0,0,0}},
                       {{0,0,0,0},{0,0,0,0}},{{0,0,0,0},{0,0,0,0}}};
    float dp[2] = {0.f, 0.f};

    union U8 { uint2 u[2]; bf16x8 v; };

    // ---- prologue: chunk0 -> buf0; chunk1 -> R; masks ch0/ch1; xfrag(0,1)
#pragma unroll
    for (int p = 0; p < 8; ++p)
        R[p] = *(const bf16x8*)&hsrc[(size_t)(p * 8) * DTH];
    mwA[0] = amr0[0]; mwA[1] = amr1[0];
    mwB[0] = amr0[2]; mwB[1] = amr1[2];
#pragma unroll
    for (int p = 0; p < 8; ++p)
        *(bf16x8*)&hxj[0][(srow + p * 8) * 256 + sdst] = R[p];
#pragma unroll
    for (int p = 0; p < 8; ++p)
        R[p] = *(const bf16x8*)&hsrc[(size_t)(64 + p * 8) * DTH];
#pragma unroll
    for (int ct = 0; ct < 4; ++ct) {
        xe[ct] = *(const uint2*)&X2T[(size_t)(ct * 16 + li) * NN + jb + w * 16 + q * 4];
        xo[ct] = *(const uint2*)&X2T[(size_t)(ct * 16 + li) * NN + jb + 64 + w * 16 + q * 4];
    }
    __syncthreads();

#define QK_GATE(CUR, CH, MW, PDST0, PDST1)                                     \
    {                                                                          \
        f32x4 s0 = {0,0,0,0}, s1 = {0,0,0,0};                                  \
        _Pragma("unroll")                                                      \
        for (int ks = 0; ks < 8; ++ks) {                                       \
            bf16x8 aj = *(const bf16x8*)&hxj[CUR][(w * 16 + li) * 256 + (((ks * 4 + q) ^ (li & 7)) * 8)]; \
            s0 = __builtin_amdgcn_mfma_f32_16x16x32_bf16(aj, afragB[0][ks], s0, 0, 0, 0); \
            s1 = __builtin_amdgcn_mfma_f32_16x16x32_bf16(aj, afragB[1][ks], s1, 0, 0, 0); \
        }                                                                      \
        int jr0 = jb + (CH) * 64 + w * 16;                                     \
        _Pragma("unroll")                                                      \
        for (int n = 0; n < 2; ++n) {                                          \
            f32x4 sv = n ? s1 : s0;                                            \
            unsigned mw = (MW)[n];                                             \
            int ig = i0 + n * 16 + li;                                         \
            _Pragma("unroll")                                                  \
            for (int r = 0; r < 4; ++r) {                                      \
                float s = sv[r];                                               \
                float sig = __builtin_amdgcn_rcpf(1.f + __expf(-s));           \
                float wv = ((mw >> ((w & 1) * 16 + q * 4 + r)) & 1u) ? __expf(sig) : 0.f; \
                int jc = jr0 + q * 4 + r;                                      \
                if (ig == jc) wv = E_CONST;                                    \
                dp[n] += wv;                                                   \
                if (n == 0) PDST0[r] = (bf16)wv; else PDST1[r] = (bf16)wv;     \
            }                                                                  \
        }                                                                      \
    }

    for (int ch = 0; ch < 64; ch += 2) {
        // ---------------- even chunk ch (buf0): QK+gate, store pe ----------
        QK_GATE(0, ch, mwA, pe0, pe1)
        // drain R(ch+1) -> buf1; refill R(ch+2), mwA(ch+2)
#pragma unroll
        for (int p = 0; p < 8; ++p)
            *(bf16x8*)&hxj[1][(srow + p * 8) * 256 + sdst] = R[p];
        if (ch < 62) {
#pragma unroll
            for (int p = 0; p < 8; ++p)
                R[p] = *(const bf16x8*)&hsrc[(size_t)((ch + 2) * 64 + p * 8) * DTH];
            mwA[0] = amr0[(ch + 2) * 2]; mwA[1] = amr1[(ch + 2) * 2];
        }
        __syncthreads();

        // ---------------- odd chunk ch+1 (buf1): QK+gate, PV pair ----------
        {
            bf16x4 po0, po1;
            QK_GATE(1, ch + 1, mwB, po0, po1)
            // PV: acc[ct][n] += X2T_frag(ct) * P^T_frag(n), K = 32 (two chunks)
#pragma unroll
            for (int n = 0; n < 2; ++n) {
                bf16x8 pf;
                bf16x4 pe = n ? pe1 : pe0;
                bf16x4 po = n ? po1 : po0;
                pf[0] = pe[0]; pf[1] = pe[1]; pf[2] = pe[2]; pf[3] = pe[3];
                pf[4] = po[0]; pf[5] = po[1]; pf[6] = po[2]; pf[7] = po[3];
#pragma unroll
                for (int ct = 0; ct < 4; ++ct) {
                    U8 xf; xf.u[0] = xe[ct]; xf.u[1] = xo[ct];
                    acc[ct][n] = __builtin_amdgcn_mfma_f32_16x16x32_bf16(xf.v, pf, acc[ct][n], 0, 0, 0);
                }
            }
            if (ch + 1 < 63) {
                // drain R(ch+2) -> buf0; refill R(ch+3), mwB(ch+3)
#pragma unroll
                for (int p = 0; p < 8; ++p)
                    *(bf16x8*)&hxj[0][(srow + p * 8) * 256 + sdst] = R[p];
#pragma unroll
                for (int p = 0; p < 8; ++p)
                    R[p] = *(const bf16x8*)&hsrc[(size_t)((ch + 3) * 64 + p * 8) * DTH];
                mwB[0] = amr0[(ch + 3) * 2]; mwB[1] = amr1[(ch + 3) * 2];
                // xfrag for next pair (ch+2, ch+3)
#pragma unroll
                for (int ct = 0; ct < 4; ++ct) {
                    xe[ct] = *(const uint2*)&X2T[(size_t)(ct * 16 + li) * NN + jb + (ch + 2) * 64 + w * 16 + q * 4];
                    xo[ct] = *(const uint2*)&X2T[(size_t)(ct * 16 + li) * NN + jb + (ch + 3) * 64 + w * 16 + q * 4];
                }
            }
            __syncthreads();
        }
    }
#undef QK_GATE

    // ---- epilogue: cross-wave reduce PV partials via LDS, plain stores ----
    float* Lf = (float*)hxj;
    float* po = pacc + (size_t)js * NN * DH;
#pragma unroll
    for (int ct = 0; ct < 4; ++ct)
#pragma unroll
        for (int n = 0; n < 2; ++n)
#pragma unroll
            for (int r = 0; r < 4; ++r)
                Lf[w * 2048 + (ct * 16 + q * 4 + r) * 32 + n * 16 + li] = acc[ct][n][r];
    __syncthreads();
#pragma unroll
    for (int p = 0; p < 8; ++p) {
        int idx = t + p * 256;
        float v = Lf[idx] + Lf[2048 + idx] + Lf[4096 + idx] + Lf[6144 + idx];
        po[(size_t)(i0 + (idx & 31)) * DH + (idx >> 5)] = v;
    }
    // denominators: reduce over q-groups in-wave, then cross-wave via LDS
    float dq0 = dp[0], dq1 = dp[1];
    dq0 += __shfl_xor(dq0, 16, 64); dq0 += __shfl_xor(dq0, 32, 64);
    dq1 += __shfl_xor(dq1, 16, 64); dq1 += __shfl_xor(dq1, 32, 64);
    __syncthreads();
    if (l < 16) { Lf[w * 32 + li] = dq0; Lf[w * 32 + 16 + li] = dq1; }
    __syncthreads();
    if (t < 32) {
        float v = Lf[t] + Lf[32 + t] + Lf[64 + t] + Lf[96 + t];
        pden[(size_t)js * NN + i0 + t] = v;
    }
}

// ---------------------------------------------------------------------------
__global__ __launch_bounds__(256) void k_finalize(const float* __restrict__ pacc,
                                                  const float* __restrict__ pden,
                                                  float* __restrict__ out)
{
    int e = blockIdx.x * 256 + threadIdx.x;
    int i = e >> 6, c = e & 63;
    float v = (pacc[e] + pacc[NN * DH + e]) / (pden[i] + pden[NN + i]);
    out[(size_t)i * 128 + 64 + c] = v > 0.f ? v : 0.01f * v;
}

// ---------------------------------------------------------------------------
extern "C" void kernel_launch(void* const* d_in, const int* in_sizes, int n_in,
                              void* d_out, int out_size, void* d_ws, size_t ws_size,
                              hipStream_t stream)
{
    const float* H     = (const float*)d_in[0];
    const float* A     = (const float*)d_in[1];
    const float* gamma = (const float*)d_in[2];
    const float* beta  = (const float*)d_in[3];
    const float* Wt    = (const float*)d_in[4];
    const float* bt    = (const float*)d_in[5];
    const float* W1    = (const float*)d_in[6];
    const float* b1    = (const float*)d_in[7];
    const float* W2    = (const float*)d_in[8];
    const float* b2    = (const float*)d_in[9];
    float* out = (float*)d_out;

    char* ws = (char*)d_ws;
    float*    bns  = (float*)(ws + OFF_BN);
    float*    pacc = (float*)(ws + OFF_PACC);
    float*    pden = (float*)(ws + OFF_PDEN);
    bf16*     Hx   = (bf16*)(ws + OFF_HX);
    bf16*     X2T  = (bf16*)(ws + OFF_X2T);
    unsigned* Am   = (unsigned*)(ws + OFF_AM);

    hipMemsetAsync(ws + OFF_BN, 0, ZERO_BYTES, stream);
    k_pack<<<8192, 256, 0, stream>>>(A, Am);
    k_bn_stats<<<256, 256, 0, stream>>>(H, bns);
    k_project<<<512, 256, 0, stream>>>(H, bns, gamma, beta, Wt, bt, W1, b1, W2, b2,
                                       Hx, X2T, out);
    k_fused<<<512, 256, 0, stream>>>(Am, Hx, X2T, pacc, pden);
    k_finalize<<<2048, 256, 0, stream>>>(pacc, pden, out);
}